// Round 13
// baseline (68.642 us; speedup 1.0000x reference)
//
#include <hip/hip_runtime.h>
#include <stdint.h>
#include <math.h>

#define NN 8192
#define EE 8192
#define DD 128

// modern JAX (jax_threefry_partitionable=True):
//   bits(idx) = o0 ^ o1 of threefry(key, (0, idx));
//   split -> subkey j = (o0, o1) of threefry(key, (0, j))
__host__ __device__ inline void tf2x32(uint32_t k0, uint32_t k1, uint32_t c0, uint32_t c1,
                                       uint32_t& o0, uint32_t& o1) {
  uint32_t ks[3] = {k0, k1, 0x1BD11BDAu ^ k0 ^ k1};
  uint32_t x0 = c0 + k0, x1 = c1 + k1;
  const uint32_t rot0[4] = {13u, 15u, 26u, 6u};
  const uint32_t rot1[4] = {17u, 29u, 16u, 24u};
#pragma unroll
  for (int i = 0; i < 5; ++i) {
#pragma unroll
    for (int r = 0; r < 4; ++r) {
      uint32_t d = (i & 1) ? rot1[r] : rot0[r];
      x0 += x1;
      x1 = (x1 << d) | (x1 >> (32u - d));
      x1 ^= x0;
    }
    x0 += ks[(i + 1) % 3];
    x1 += ks[(i + 2) % 3] + (uint32_t)(i + 1);
  }
  o0 = x0; o1 = x1;
}

__device__ inline uint32_t rbits32(uint32_t k0, uint32_t k1, uint32_t idx) {
  uint32_t o0, o1;
  tf2x32(k0, k1, 0u, idx, o0, o1);
  return o0 ^ o1;
}

__device__ inline float u01(uint32_t b) {
  return __uint_as_float((b >> 9) | 0x3f800000u) - 1.0f;
}

// XLA f32 erf_inv polynomial
__device__ inline float erfinv_f32(float x) {
  float w = -log1pf(-x * x);
  float p;
  if (w < 5.0f) {
    w -= 2.5f;
    p = 2.81022636e-08f;
    p = fmaf(p, w, 3.43273939e-07f);
    p = fmaf(p, w, -3.5233877e-06f);
    p = fmaf(p, w, -4.39150654e-06f);
    p = fmaf(p, w, 0.00021858087f);
    p = fmaf(p, w, -0.00125372503f);
    p = fmaf(p, w, -0.00417768164f);
    p = fmaf(p, w, 0.246640727f);
    p = fmaf(p, w, 1.50140941f);
  } else {
    w = sqrtf(w) - 3.0f;
    p = -0.000200214257f;
    p = fmaf(p, w, 0.000100950558f);
    p = fmaf(p, w, 0.00134934322f);
    p = fmaf(p, w, -0.00367342844f);
    p = fmaf(p, w, 0.00573950773f);
    p = fmaf(p, w, -0.0076224613f);
    p = fmaf(p, w, 0.00943887047f);
    p = fmaf(p, w, 1.00167406f);
    p = fmaf(p, w, 2.83297682f);
  }
  return p * x;
}

// A (fused): per-node gen decision (bit-identical to round-11 k_gens) +
// query row for GENERATING nodes only (~60 quads take the branch; ~2 MFLOP).
// Accumulation order per output col identical to old k_queries (bq init, k asc).
__global__ __launch_bounds__(256)
void k_gens(const float* __restrict__ nodes, const float* __restrict__ Wp,
            const float* __restrict__ bp, const float* __restrict__ anodes,
            const float* __restrict__ Wq, const float* __restrict__ bq,
            int* __restrict__ gens, float* __restrict__ queries,
            uint32_t kp0, uint32_t kp1) {
  int t = blockIdx.x * 256 + threadIdx.x;
  int i = t >> 2, qd = t & 3;
  if (i >= NN) return;
  const float4* row = (const float4*)(nodes + (size_t)i * DD);
  const float4* w = (const float4*)Wp;
  float acc = 0.f;
#pragma unroll
  for (int c = 0; c < 8; ++c) {
    int k4 = qd + 4 * c;
    float4 a = row[k4], b = w[k4];
    acc = fmaf(a.x, b.x, acc); acc = fmaf(a.y, b.y, acc);
    acc = fmaf(a.z, b.z, acc); acc = fmaf(a.w, b.w, acc);
  }
  acc += __shfl_xor(acc, 1, 4);
  acc += __shfl_xor(acc, 2, 4);
  int dec = 0;
  if (qd == 0) {
    float prob = 1.0f / (1.0f + expf(-(acc + bp[0])));
    uint32_t b = rbits32(kp0, kp1, (uint32_t)i);
    dec = (u01(b) < prob * anodes[i]) ? 1 : 0;
    gens[i] = dec;
  }
  dec = __shfl(dec, 0, 4);   // broadcast decision to the node's 4-lane quad

  if (dec) {
    // query row: lane qd computes cols [qd*32, qd*32+32) as 8 float4 accs
    const float4* wq4 = (const float4*)Wq;   // row stride 32 float4s
    const float* nrow = nodes + (size_t)i * DD;
    float4 a4[8];
    const float4* bq4 = (const float4*)bq;
#pragma unroll
    for (int j4 = 0; j4 < 8; ++j4) a4[j4] = bq4[qd * 8 + j4];
    for (int k = 0; k < DD; ++k) {
      float nv = nrow[k];                    // L1/L2-hot scalar, quad-coalesced
#pragma unroll
      for (int j4 = 0; j4 < 8; ++j4) {
        float4 wv = wq4[(size_t)k * 32 + qd * 8 + j4];
        a4[j4].x = fmaf(nv, wv.x, a4[j4].x);
        a4[j4].y = fmaf(nv, wv.y, a4[j4].y);
        a4[j4].z = fmaf(nv, wv.z, a4[j4].z);
        a4[j4].w = fmaf(nv, wv.w, a4[j4].w);
      }
    }
    float4* qout = (float4*)(queries + (size_t)i * DD);
#pragma unroll
    for (int j4 = 0; j4 < 8; ++j4) qout[qd * 8 + j4] = a4[j4];
  }
}

// B: scans (wave-shuffle parallel), gen_list, naedges/mask_new, zero partials
__global__ __launch_bounds__(256)
void k_scan(const float* __restrict__ aedges, const int* __restrict__ gens,
            int* __restrict__ gen_list, float* __restrict__ mask_new,
            float* __restrict__ naedges_out, int* __restrict__ scal,
            unsigned long long* __restrict__ partial) {
  __shared__ int P[EE];     // 32KB
  __shared__ int aux[8];    // wave totals: [0..3]=aedges, [4..7]=gens
  int tid = threadIdx.x;
  int base = tid * 32;
  int lane = tid & 63, wid = tid >> 6;

  int av[32]; int aloc = 0;
  {
    const float4* a4 = (const float4*)(aedges + base);
#pragma unroll
    for (int k4 = 0; k4 < 8; ++k4) {
      float4 x = a4[k4];
      av[4 * k4 + 0] = (x.x > 0.f); av[4 * k4 + 1] = (x.y > 0.f);
      av[4 * k4 + 2] = (x.z > 0.f); av[4 * k4 + 3] = (x.w > 0.f);
    }
#pragma unroll
    for (int k = 0; k < 32; ++k) aloc += av[k];
  }
  int incl = aloc;
#pragma unroll
  for (int d = 1; d < 64; d <<= 1) {
    int o = __shfl_up(incl, d, 64);
    if (lane >= d) incl += o;
  }
  if (lane == 63) aux[wid] = incl;

  int g[32]; int gloc = 0;
  {
    const int4* g4 = (const int4*)(gens + base);
#pragma unroll
    for (int k4 = 0; k4 < 8; ++k4) {
      int4 x = g4[k4];
      g[4 * k4 + 0] = x.x; g[4 * k4 + 1] = x.y;
      g[4 * k4 + 2] = x.z; g[4 * k4 + 3] = x.w;
    }
#pragma unroll
    for (int k = 0; k < 32; ++k) gloc += g[k];
  }
  int incg = gloc;
#pragma unroll
  for (int d = 1; d < 64; d <<= 1) {
    int o = __shfl_up(incg, d, 64);
    if (lane >= d) incg += o;
  }
  if (lane == 63) aux[4 + wid] = incg;
  __syncthreads();

  int e_active = aux[0] + aux[1] + aux[2] + aux[3];
  int total = aux[4] + aux[5] + aux[6] + aux[7];
  int wpreA = 0, wpreG = 0;
  for (int ww = 0; ww < wid; ++ww) { wpreA += aux[ww]; wpreG += aux[4 + ww]; }

  {
    int run = wpreA + incl - aloc;   // exclusive prefix for this thread's chunk
#pragma unroll
    for (int k = 0; k < 32; ++k) { run += av[k]; P[base + k] = run; }
  }
  {
    int rank = wpreG + incg - gloc;
#pragma unroll
    for (int k = 0; k < 32; ++k) {
      if (g[k]) {
        if (e_active + rank < EE) gen_list[rank] = base + k;
        rank++;
      }
    }
  }
  if (tid == 0) { scal[0] = e_active; scal[1] = total; }

  // zero partial accumulators (total*32 slots)
  for (int idx = tid; idx < total * 32; idx += 256) partial[idx] = 0ull;

  int allowed = EE - e_active - 1;
  int n_gens = total;
  if (n_gens > allowed) n_gens = allowed;
  if (n_gens < 0) n_gens = 0;

  __syncthreads();   // P fully written before cross-chunk windowed reads
#pragma unroll
  for (int k = 0; k < 32; ++k) {
    int j = base + k;
    int lo = j - n_gens - 1;
    int wsum = P[j] - (lo >= 0 ? P[lo] : 0);
    float dil = (wsum > 0) ? 1.f : 0.f;
    if (j == EE - 1) dil = 0.f;
    naedges_out[j] = dil;
    mask_new[j] = dil * (1.0f - (float)av[k]);
  }
}

// C: (node-chunk x rank-tile) score+gumbel argmax; hierarchical merge:
// block winner -> partial[r][x>>3] (8-way contention max, 32 slots/rank)
// key = order-preserving-float(v) << 32 | (NN-1-j)  -> max key == (max v, min j)
// LDS: rotation swizzle (k4+jl)&31 -> bank-conflict-free (verified round 10: 0)
// queries indexed by NODE ID (written in k_gens for generating nodes).
__global__ __launch_bounds__(256)
void k_score(const float* __restrict__ nodes, const float* __restrict__ anodes,
             const float* __restrict__ queries, const int* __restrict__ gen_list,
             const int* __restrict__ scal, unsigned long long* __restrict__ partial,
             uint32_t ks0, uint32_t ks1) {
  __shared__ float4 nd[32 * 32];  // 32 node rows, rotation-swizzled float4 cols
  __shared__ float q[8][DD];
  __shared__ float an[32];
  __shared__ int gi[8];
  int tid = threadIdx.x;
  int j0 = blockIdx.x * 32;
  int total = scal[1];
  int rt0 = blockIdx.y * 8;
  if (rt0 >= total) return;     // dead rank tile: exit before staging

  {
    int jj = tid >> 3, sub = tid & 7;
    const float4* src = (const float4*)(nodes + (size_t)(j0 + jj) * DD);
#pragma unroll
    for (int c = 0; c < 4; ++c) {
      int k4 = sub + 8 * c;
      nd[jj * 32 + ((k4 + jj) & 31)] = src[k4];   // rotation swizzle
    }
    if (tid < 32) an[tid] = anodes[j0 + tid];
  }

  int rr = tid >> 5, jl = tid & 31;
  for (int rb = rt0; rb < total; rb += 8 * gridDim.y) {
    __syncthreads();
    {
      int lr = rb + (tid >> 5);
      int k4 = tid & 31;
      if (lr < total) {
        int id = gen_list[lr];            // redundant per-lane load, L2-hot
        ((float4*)q[tid >> 5])[k4] = ((const float4*)(queries + (size_t)id * DD))[k4];
        if (k4 == 0) gi[tid >> 5] = id;
      }
    }
    __syncthreads();

    int r = rb + rr;
    if (r < total) {
      const float4* qv = (const float4*)q[rr];
      float acc = 0.f;
#pragma unroll
      for (int k4 = 0; k4 < 32; ++k4) {
        float4 n = nd[jl * 32 + ((k4 + jl) & 31)];
        float4 qq = qv[k4];
        acc = fmaf(n.x, qq.x, acc); acc = fmaf(n.y, qq.y, acc);
        acc = fmaf(n.z, qq.z, acc); acc = fmaf(n.w, qq.w, acc);
      }
      int j = j0 + jl;
      float sc = fminf(fmaxf(acc, -1e4f), 1e4f);
      sc -= (1.0f - an[jl]) * 1e10f;
      uint32_t bidx = (uint32_t)gi[rr] * NN + (uint32_t)j;
      uint32_t b = rbits32(ks0, ks1, bidx);
      float u = fmaxf(1.17549435e-38f, u01(b));
      float gmb = -logf(-logf(u));
      float v = sc + gmb;
      int jbest = j;
#pragma unroll
      for (int m = 16; m; m >>= 1) {
        float ov = __shfl_xor(v, m, 32);
        int oj = __shfl_xor(jbest, m, 32);
        if (ov > v || (ov == v && oj < jbest)) { v = ov; jbest = oj; }
      }
      if (jl == 0) {
        uint32_t fb = __float_as_uint(v);
        fb = (fb & 0x80000000u) ? ~fb : (fb | 0x80000000u);
        unsigned long long key =
            ((unsigned long long)fb << 32) | (uint32_t)(NN - 1 - jbest);
        atomicMax(&partial[(size_t)r * 32 + (blockIdx.x >> 3)], key);
      }
    }
  }
}

// D (fused): new_edges noise + nsend/nrec with inline partial-max decode
__global__ __launch_bounds__(256)
void k_post(const float* __restrict__ edges, const float* __restrict__ mask_new,
            const int* __restrict__ send, const int* __restrict__ rec,
            const int* __restrict__ gen_list,
            const unsigned long long* __restrict__ partial,
            const int* __restrict__ scal,
            float* __restrict__ out_edges, float* __restrict__ out_nsend,
            float* __restrict__ out_nrec, uint32_t ke0, uint32_t ke1) {
  int t = blockIdx.x * 256 + threadIdx.x;   // float4 index
  int idx = t * 4;
  int e = idx >> 7;
  float m = mask_new[e];
  float4 v = ((const float4*)edges)[t];
  if (m > 0.f) {
    float* pv = &v.x;
#pragma unroll
    for (int k = 0; k < 4; ++k) {
      uint32_t b = rbits32(ke0, ke1, (uint32_t)(idx + k));
      float u = u01(b);
      float x = fmaf(u, 2.0f, -0.99999994f);
      x = fmaxf(-0.99999994f, x);
      float nrm = 1.41421354f * erfinv_f32(x);
      pv[k] += nrm * m;
    }
  }
  ((float4*)out_edges)[t] = v;

  if (t < EE) {
    int e_active = scal[0], total = scal[1];
    float mm = mask_new[t];
    float sf = (float)send[t] * (1.0f - mm);
    float rf = (float)rec[t] * (1.0f - mm);
    int r = t - e_active;
    if (r >= 0 && r < total) {
      unsigned long long best = 0ull;
      const unsigned long long* pp = partial + (size_t)r * 32;
#pragma unroll
      for (int p = 0; p < 32; ++p) { unsigned long long x = pp[p]; if (x > best) best = x; }
      int i = gen_list[r];
      int jsel = (NN - 1) - (int)(best & 0xFFFFFFFFull);
      sf += (float)i;
      rf += (float)jsel;
    }
    out_nsend[t] = (float)(int)sf;
    out_nrec[t] = (float)(int)rf;
  }
}

extern "C" void kernel_launch(void* const* d_in, const int* in_sizes, int n_in,
                              void* d_out, int out_size, void* d_ws, size_t ws_size,
                              hipStream_t stream) {
  const float* nodes  = (const float*)d_in[0];
  const float* edges  = (const float*)d_in[1];
  const int*   rec    = (const int*)d_in[2];
  const int*   send   = (const int*)d_in[3];
  const float* anodes = (const float*)d_in[4];
  const float* aedges = (const float*)d_in[5];
  const float* Wq     = (const float*)d_in[6];
  const float* bq     = (const float*)d_in[7];
  const float* Wp     = (const float*)d_in[8];
  const float* bp     = (const float*)d_in[9];

  float* out        = (float*)d_out;
  float* out_edges  = out;                    // E*D
  float* out_nsend  = out + (size_t)EE * DD;  // E
  float* out_nrec   = out_nsend + EE;         // E
  float* out_naedge = out_nrec + EE;          // E

  char* w = (char*)d_ws;
  int*   gens     = (int*)w;                          // 32KB
  int*   gen_list = (int*)(w + 32768);                // 32KB
  int*   scal     = (int*)(w + 65536);                // 256B
  float* mask_new = (float*)(w + 65792);              // 32KB -> ends 98560
  unsigned long long* partial = (unsigned long long*)(w + 98560);  // 6144*32*8 = 1.5MB
  float* queries  = (float*)(w + 98560 + 6144 * 32 * 8);           // NN*DD*4 = 4MB (sparse)

  uint32_t kp0, kp1, ke0, ke1, ks0, ks1;
  tf2x32(0u, 42u, 0u, 0u, kp0, kp1);
  tf2x32(0u, 42u, 0u, 1u, ke0, ke1);
  tf2x32(0u, 42u, 0u, 2u, ks0, ks1);

  k_gens<<<NN * 4 / 256, 256, 0, stream>>>(nodes, Wp, bp, anodes, Wq, bq,
                                           gens, queries, kp0, kp1);
  k_scan<<<1, 256, 0, stream>>>(aedges, gens, gen_list, mask_new, out_naedge, scal, partial);
  k_score<<<dim3(NN / 32, 8), 256, 0, stream>>>(nodes, anodes, queries, gen_list, scal,
                                                partial, ks0, ks1);
  k_post<<<(EE * DD / 4) / 256, 256, 0, stream>>>(edges, mask_new, send, rec, gen_list,
                                                  partial, scal, out_edges, out_nsend,
                                                  out_nrec, ke0, ke1);
}

// Round 14
// 42.844 us; speedup vs baseline: 1.6021x; 1.6021x over previous
//
#include <hip/hip_runtime.h>
#include <stdint.h>
#include <math.h>

#define NN 8192
#define EE 8192
#define DD 128

// modern JAX (jax_threefry_partitionable=True):
//   bits(idx) = o0 ^ o1 of threefry(key, (0, idx));
//   split -> subkey j = (o0, o1) of threefry(key, (0, j))
__host__ __device__ inline void tf2x32(uint32_t k0, uint32_t k1, uint32_t c0, uint32_t c1,
                                       uint32_t& o0, uint32_t& o1) {
  uint32_t ks[3] = {k0, k1, 0x1BD11BDAu ^ k0 ^ k1};
  uint32_t x0 = c0 + k0, x1 = c1 + k1;
  const uint32_t rot0[4] = {13u, 15u, 26u, 6u};
  const uint32_t rot1[4] = {17u, 29u, 16u, 24u};
#pragma unroll
  for (int i = 0; i < 5; ++i) {
#pragma unroll
    for (int r = 0; r < 4; ++r) {
      uint32_t d = (i & 1) ? rot1[r] : rot0[r];
      x0 += x1;
      x1 = (x1 << d) | (x1 >> (32u - d));
      x1 ^= x0;
    }
    x0 += ks[(i + 1) % 3];
    x1 += ks[(i + 2) % 3] + (uint32_t)(i + 1);
  }
  o0 = x0; o1 = x1;
}

__device__ inline uint32_t rbits32(uint32_t k0, uint32_t k1, uint32_t idx) {
  uint32_t o0, o1;
  tf2x32(k0, k1, 0u, idx, o0, o1);
  return o0 ^ o1;
}

__device__ inline float u01(uint32_t b) {
  return __uint_as_float((b >> 9) | 0x3f800000u) - 1.0f;
}

// XLA f32 erf_inv polynomial
__device__ inline float erfinv_f32(float x) {
  float w = -log1pf(-x * x);
  float p;
  if (w < 5.0f) {
    w -= 2.5f;
    p = 2.81022636e-08f;
    p = fmaf(p, w, 3.43273939e-07f);
    p = fmaf(p, w, -3.5233877e-06f);
    p = fmaf(p, w, -4.39150654e-06f);
    p = fmaf(p, w, 0.00021858087f);
    p = fmaf(p, w, -0.00125372503f);
    p = fmaf(p, w, -0.00417768164f);
    p = fmaf(p, w, 0.246640727f);
    p = fmaf(p, w, 1.50140941f);
  } else {
    w = sqrtf(w) - 3.0f;
    p = -0.000200214257f;
    p = fmaf(p, w, 0.000100950558f);
    p = fmaf(p, w, 0.00134934322f);
    p = fmaf(p, w, -0.00367342844f);
    p = fmaf(p, w, 0.00573950773f);
    p = fmaf(p, w, -0.0076224613f);
    p = fmaf(p, w, 0.00943887047f);
    p = fmaf(p, w, 1.00167406f);
    p = fmaf(p, w, 2.83297682f);
  }
  return p * x;
}

// A: per-node gen decision; 4 lanes per row for coalesced 64B segments
__global__ __launch_bounds__(256)
void k_gens(const float* __restrict__ nodes, const float* __restrict__ Wp,
            const float* __restrict__ bp, const float* __restrict__ anodes,
            int* __restrict__ gens, uint32_t kp0, uint32_t kp1) {
  int t = blockIdx.x * 256 + threadIdx.x;
  int i = t >> 2, qd = t & 3;
  if (i >= NN) return;
  const float4* row = (const float4*)(nodes + (size_t)i * DD);
  const float4* w = (const float4*)Wp;
  float acc = 0.f;
#pragma unroll
  for (int c = 0; c < 8; ++c) {
    int k4 = qd + 4 * c;
    float4 a = row[k4], b = w[k4];
    acc = fmaf(a.x, b.x, acc); acc = fmaf(a.y, b.y, acc);
    acc = fmaf(a.z, b.z, acc); acc = fmaf(a.w, b.w, acc);
  }
  acc += __shfl_xor(acc, 1, 4);
  acc += __shfl_xor(acc, 2, 4);
  if (qd == 0) {
    float prob = 1.0f / (1.0f + expf(-(acc + bp[0])));
    uint32_t b = rbits32(kp0, kp1, (uint32_t)i);
    gens[i] = (u01(b) < prob * anodes[i]) ? 1 : 0;
  }
}

// B: scans (wave-shuffle parallel), gen_list, naedges/mask_new, zero partials
__global__ __launch_bounds__(256)
void k_scan(const float* __restrict__ aedges, const int* __restrict__ gens,
            int* __restrict__ gen_list, float* __restrict__ mask_new,
            float* __restrict__ naedges_out, int* __restrict__ scal,
            unsigned long long* __restrict__ partial) {
  __shared__ int P[EE];     // 32KB
  __shared__ int aux[8];    // wave totals: [0..3]=aedges, [4..7]=gens
  int tid = threadIdx.x;
  int base = tid * 32;
  int lane = tid & 63, wid = tid >> 6;

  int av[32]; int aloc = 0;
  {
    const float4* a4 = (const float4*)(aedges + base);
#pragma unroll
    for (int k4 = 0; k4 < 8; ++k4) {
      float4 x = a4[k4];
      av[4 * k4 + 0] = (x.x > 0.f); av[4 * k4 + 1] = (x.y > 0.f);
      av[4 * k4 + 2] = (x.z > 0.f); av[4 * k4 + 3] = (x.w > 0.f);
    }
#pragma unroll
    for (int k = 0; k < 32; ++k) aloc += av[k];
  }
  int incl = aloc;
#pragma unroll
  for (int d = 1; d < 64; d <<= 1) {
    int o = __shfl_up(incl, d, 64);
    if (lane >= d) incl += o;
  }
  if (lane == 63) aux[wid] = incl;

  int g[32]; int gloc = 0;
  {
    const int4* g4 = (const int4*)(gens + base);
#pragma unroll
    for (int k4 = 0; k4 < 8; ++k4) {
      int4 x = g4[k4];
      g[4 * k4 + 0] = x.x; g[4 * k4 + 1] = x.y;
      g[4 * k4 + 2] = x.z; g[4 * k4 + 3] = x.w;
    }
#pragma unroll
    for (int k = 0; k < 32; ++k) gloc += g[k];
  }
  int incg = gloc;
#pragma unroll
  for (int d = 1; d < 64; d <<= 1) {
    int o = __shfl_up(incg, d, 64);
    if (lane >= d) incg += o;
  }
  if (lane == 63) aux[4 + wid] = incg;
  __syncthreads();

  int e_active = aux[0] + aux[1] + aux[2] + aux[3];
  int total = aux[4] + aux[5] + aux[6] + aux[7];
  int wpreA = 0, wpreG = 0;
  for (int ww = 0; ww < wid; ++ww) { wpreA += aux[ww]; wpreG += aux[4 + ww]; }

  {
    int run = wpreA + incl - aloc;   // exclusive prefix for this thread's chunk
#pragma unroll
    for (int k = 0; k < 32; ++k) { run += av[k]; P[base + k] = run; }
  }
  {
    int rank = wpreG + incg - gloc;
#pragma unroll
    for (int k = 0; k < 32; ++k) {
      if (g[k]) {
        if (e_active + rank < EE) gen_list[rank] = base + k;
        rank++;
      }
    }
  }
  if (tid == 0) { scal[0] = e_active; scal[1] = total; }

  // zero partial accumulators (total*32 slots)
  for (int idx = tid; idx < total * 32; idx += 256) partial[idx] = 0ull;

  int allowed = EE - e_active - 1;
  int n_gens = total;
  if (n_gens > allowed) n_gens = allowed;
  if (n_gens < 0) n_gens = 0;

  __syncthreads();   // P fully written before cross-chunk windowed reads
#pragma unroll
  for (int k = 0; k < 32; ++k) {
    int j = base + k;
    int lo = j - n_gens - 1;
    int wsum = P[j] - (lo >= 0 ? P[lo] : 0);
    float dil = (wsum > 0) ? 1.f : 0.f;
    if (j == EE - 1) dil = 0.f;
    naedges_out[j] = dil;
    mask_new[j] = dil * (1.0f - (float)av[k]);
  }
}

// C1: queries[r] = nodes[gen_list[r]] @ Wq + bq, for r < total
__global__ __launch_bounds__(128)
void k_queries(const float* __restrict__ nodes, const float* __restrict__ Wq,
               const float* __restrict__ bq, const int* __restrict__ gen_list,
               const int* __restrict__ scal, float* __restrict__ queries) {
  __shared__ float ni[DD];
  int tid = threadIdx.x;
  int total = scal[1];
  for (int r = blockIdx.x; r < total; r += gridDim.x) {
    int i = gen_list[r];
    ni[tid] = nodes[(size_t)i * DD + tid];
    __syncthreads();
    float acc = bq[tid];
    for (int k = 0; k < DD; ++k) acc = fmaf(ni[k], Wq[k * DD + tid], acc);
    queries[(size_t)r * DD + tid] = acc;
    __syncthreads();
  }
}

// C2: (node-chunk x rank-tile) score+gumbel argmax; hierarchical merge:
// block winner -> partial[r][x>>3] (8-way contention max, 32 slots/rank)
// key = order-preserving-float(v) << 32 | (NN-1-j)  -> max key == (max v, min j)
// LDS: rotation swizzle (k4+jl)&31 -> bank-conflict-free (verified round 10: 0)
__global__ __launch_bounds__(256)
void k_score(const float* __restrict__ nodes, const float* __restrict__ anodes,
             const float* __restrict__ queries, const int* __restrict__ gen_list,
             const int* __restrict__ scal, unsigned long long* __restrict__ partial,
             uint32_t ks0, uint32_t ks1) {
  __shared__ float4 nd[32 * 32];  // 32 node rows, rotation-swizzled float4 cols
  __shared__ float q[8][DD];
  __shared__ float an[32];
  __shared__ int gi[8];
  int tid = threadIdx.x;
  int j0 = blockIdx.x * 32;
  int total = scal[1];
  int rt0 = blockIdx.y * 8;
  if (rt0 >= total) return;     // dead rank tile: exit before staging

  {
    int jj = tid >> 3, sub = tid & 7;
    const float4* src = (const float4*)(nodes + (size_t)(j0 + jj) * DD);
#pragma unroll
    for (int c = 0; c < 4; ++c) {
      int k4 = sub + 8 * c;
      nd[jj * 32 + ((k4 + jj) & 31)] = src[k4];   // rotation swizzle
    }
    if (tid < 32) an[tid] = anodes[j0 + tid];
  }

  int rr = tid >> 5, jl = tid & 31;
  for (int rb = rt0; rb < total; rb += 8 * gridDim.y) {
    __syncthreads();
    {
      int lr = rb + (tid >> 5);
      int k4 = tid & 31;
      if (lr < total) {
        ((float4*)q[tid >> 5])[k4] = ((const float4*)(queries + (size_t)lr * DD))[k4];
        if (k4 == 0) gi[tid >> 5] = gen_list[lr];
      }
    }
    __syncthreads();

    int r = rb + rr;
    if (r < total) {
      const float4* qv = (const float4*)q[rr];
      float acc = 0.f;
#pragma unroll
      for (int k4 = 0; k4 < 32; ++k4) {
        float4 n = nd[jl * 32 + ((k4 + jl) & 31)];
        float4 qq = qv[k4];
        acc = fmaf(n.x, qq.x, acc); acc = fmaf(n.y, qq.y, acc);
        acc = fmaf(n.z, qq.z, acc); acc = fmaf(n.w, qq.w, acc);
      }
      int j = j0 + jl;
      float sc = fminf(fmaxf(acc, -1e4f), 1e4f);
      sc -= (1.0f - an[jl]) * 1e10f;
      uint32_t bidx = (uint32_t)gi[rr] * NN + (uint32_t)j;
      uint32_t b = rbits32(ks0, ks1, bidx);
      float u = fmaxf(1.17549435e-38f, u01(b));
      float gmb = -logf(-logf(u));
      float v = sc + gmb;
      int jbest = j;
#pragma unroll
      for (int m = 16; m; m >>= 1) {
        float ov = __shfl_xor(v, m, 32);
        int oj = __shfl_xor(jbest, m, 32);
        if (ov > v || (ov == v && oj < jbest)) { v = ov; jbest = oj; }
      }
      if (jl == 0) {
        uint32_t fb = __float_as_uint(v);
        fb = (fb & 0x80000000u) ? ~fb : (fb | 0x80000000u);
        unsigned long long key =
            ((unsigned long long)fb << 32) | (uint32_t)(NN - 1 - jbest);
        atomicMax(&partial[(size_t)r * 32 + (blockIdx.x >> 3)], key);
      }
    }
  }
}

// D (fused): new_edges noise + nsend/nrec with inline partial-max decode
__global__ __launch_bounds__(256)
void k_post(const float* __restrict__ edges, const float* __restrict__ mask_new,
            const int* __restrict__ send, const int* __restrict__ rec,
            const int* __restrict__ gen_list,
            const unsigned long long* __restrict__ partial,
            const int* __restrict__ scal,
            float* __restrict__ out_edges, float* __restrict__ out_nsend,
            float* __restrict__ out_nrec, uint32_t ke0, uint32_t ke1) {
  int t = blockIdx.x * 256 + threadIdx.x;   // float4 index
  int idx = t * 4;
  int e = idx >> 7;
  float m = mask_new[e];
  float4 v = ((const float4*)edges)[t];
  if (m > 0.f) {
    float* pv = &v.x;
#pragma unroll
    for (int k = 0; k < 4; ++k) {
      uint32_t b = rbits32(ke0, ke1, (uint32_t)(idx + k));
      float u = u01(b);
      float x = fmaf(u, 2.0f, -0.99999994f);
      x = fmaxf(-0.99999994f, x);
      float nrm = 1.41421354f * erfinv_f32(x);
      pv[k] += nrm * m;
    }
  }
  ((float4*)out_edges)[t] = v;

  if (t < EE) {
    int e_active = scal[0], total = scal[1];
    float mm = mask_new[t];
    float sf = (float)send[t] * (1.0f - mm);
    float rf = (float)rec[t] * (1.0f - mm);
    int r = t - e_active;
    if (r >= 0 && r < total) {
      unsigned long long best = 0ull;
      const unsigned long long* pp = partial + (size_t)r * 32;
#pragma unroll
      for (int p = 0; p < 32; ++p) { unsigned long long x = pp[p]; if (x > best) best = x; }
      int i = gen_list[r];
      int jsel = (NN - 1) - (int)(best & 0xFFFFFFFFull);
      sf += (float)i;
      rf += (float)jsel;
    }
    out_nsend[t] = (float)(int)sf;
    out_nrec[t] = (float)(int)rf;
  }
}

extern "C" void kernel_launch(void* const* d_in, const int* in_sizes, int n_in,
                              void* d_out, int out_size, void* d_ws, size_t ws_size,
                              hipStream_t stream) {
  const float* nodes  = (const float*)d_in[0];
  const float* edges  = (const float*)d_in[1];
  const int*   rec    = (const int*)d_in[2];
  const int*   send   = (const int*)d_in[3];
  const float* anodes = (const float*)d_in[4];
  const float* aedges = (const float*)d_in[5];
  const float* Wq     = (const float*)d_in[6];
  const float* bq     = (const float*)d_in[7];
  const float* Wp     = (const float*)d_in[8];
  const float* bp     = (const float*)d_in[9];

  float* out        = (float*)d_out;
  float* out_edges  = out;                    // E*D
  float* out_nsend  = out + (size_t)EE * DD;  // E
  float* out_nrec   = out_nsend + EE;         // E
  float* out_naedge = out_nrec + EE;          // E

  char* w = (char*)d_ws;
  int*   gens     = (int*)w;                          // 32KB
  int*   gen_list = (int*)(w + 32768);                // 32KB
  int*   scal     = (int*)(w + 65536);                // 256B
  float* mask_new = (float*)(w + 65792);              // 32KB -> ends 98560
  unsigned long long* partial = (unsigned long long*)(w + 98560);  // 6144*32*8 = 1.5MB
  float* queries  = (float*)(w + 98560 + 6144 * 32 * 8);           // total*DD*4

  uint32_t kp0, kp1, ke0, ke1, ks0, ks1;
  tf2x32(0u, 42u, 0u, 0u, kp0, kp1);
  tf2x32(0u, 42u, 0u, 1u, ke0, ke1);
  tf2x32(0u, 42u, 0u, 2u, ks0, ks1);

  k_gens<<<NN * 4 / 256, 256, 0, stream>>>(nodes, Wp, bp, anodes, gens, kp0, kp1);
  k_scan<<<1, 256, 0, stream>>>(aedges, gens, gen_list, mask_new, out_naedge, scal, partial);
  k_queries<<<128, 128, 0, stream>>>(nodes, Wq, bq, gen_list, scal, queries);
  k_score<<<dim3(NN / 32, 16), 256, 0, stream>>>(nodes, anodes, queries, gen_list, scal,
                                                 partial, ks0, ks1);
  k_post<<<(EE * DD / 4) / 256, 256, 0, stream>>>(edges, mask_new, send, rec, gen_list,
                                                  partial, scal, out_edges, out_nsend,
                                                  out_nrec, ke0, ke1);
}